// Round 13
// baseline (96.074 us; speedup 1.0000x reference)
//
#include <hip/hip_runtime.h>
#include <hip/hip_bf16.h>
#include <stdint.h>

#define NB 8
#define NT 2048
#define NC 1024
#define NH 64

// DIAGNOSTIC BUILD: qkv_proj body repeated 2x, attn_fused body repeated 3x
// (idempotent; lifts per-dispatch duration above the 39us ws-poison fills so
// rocprof top-5 finally shows OUR kernels with counters). True per-kernel
// time = dur_us / REP. Remove REP loops next round.

typedef __attribute__((ext_vector_type(8))) short bf16x8;
typedef __attribute__((ext_vector_type(4))) float f32x4;

#define MFMA(a, b, c) __builtin_amdgcn_mfma_f32_16x16x32_bf16((a), (b), (c), 0, 0, 0)

static __device__ __forceinline__ short f2bf(float f) {
  union { float f; uint32_t u; } v; v.f = f;
  uint32_t r = v.u + 0x7FFFu + ((v.u >> 16) & 1u);  // RNE bf16
  return (short)(r >> 16);
}
static __device__ __forceinline__ float bf2f(short h) {
  union { uint32_t u; float f; } v; v.u = ((uint32_t)(uint16_t)h) << 16;
  return v.f;
}
static __device__ __forceinline__ void gload_lds16(const void* g, void* l) {
  __builtin_amdgcn_global_load_lds(
      (const __attribute__((address_space(1))) uint32_t*)g,
      (__attribute__((address_space(3))) uint32_t*)l, 16, 0, 0);
}

// ---------------------------------------------------------------------------
// Kernel 0: build Wt[192][1024] bf16 = concat(Wq^T * 0.125*log2e, Wk^T, Wv^T)
// ---------------------------------------------------------------------------
__global__ __launch_bounds__(256) void w_prep(const float* __restrict__ Wq,
                                              const float* __restrict__ Wk,
                                              const float* __restrict__ Wv,
                                              short* __restrict__ Wt) {
  __shared__ short tile[64][68];
  const int blk = blockIdx.x;          // 48 blocks: 3 mats x 16 k-tiles
  const int mat = blk / 16;
  const int k0 = (blk % 16) * 64;
  const float* W = (mat == 0) ? Wq : (mat == 1) ? Wk : Wv;
  const float scale = (mat == 0) ? 0.125f * 1.44269504088896f : 1.0f;
  const int tid = threadIdx.x;
  {
    int kk = tid >> 2;
    int h0 = (tid & 3) * 16;
    const float* src = W + (size_t)(k0 + kk) * NH + h0;
#pragma unroll
    for (int i = 0; i < 16; ++i) tile[kk][h0 + i] = f2bf(src[i] * scale);
  }
  __syncthreads();
  {
    int j = tid >> 2;
    int kk0 = (tid & 3) * 16;
    bf16x8 t0, t1;
#pragma unroll
    for (int i = 0; i < 8; ++i) { t0[i] = tile[kk0 + i][j]; t1[i] = tile[kk0 + 8 + i][j]; }
    short* dst = Wt + (size_t)(mat * 64 + j) * NC + k0 + kk0;
    *(bf16x8*)dst = t0;
    *(bf16x8*)(dst + 8) = t1;
  }
}

// ---------------------------------------------------------------------------
// Kernel 1: QKV projection v5 (R8-proven) with REP=2 diagnostic loop.
// 512 blocks x 32 rows, 8 waves (512 thr). K-step 64, double-buffered
// global_load_lds w16, XOR-swizzled source. V transposed: VTo[(b*64+h)][t].
// ---------------------------------------------------------------------------
__global__ __launch_bounds__(512) void qkv_proj(const float* __restrict__ x,
                                                const short* __restrict__ Wt,
                                                short* __restrict__ Qo,
                                                short* __restrict__ Ko,
                                                short* __restrict__ VTo) {
  __shared__ char lds_raw[2][32768];
  const int tid = threadIdx.x;
  const int lane = tid & 63;
  const int wave = tid >> 6;             // 0..7
  const int l15 = lane & 15;
  const int hi = lane >> 4;
  const int m0 = blockIdx.x * 32;
  const int wr = wave & 1;               // row group (16 rows)
  const int wc = wave >> 1;              // col group (48 cols)

  int xr, xc;
  {
    int off = tid * 16;
    int ol = off ^ (((off >> 8) & 7) << 4);
    xr = ol >> 8; xc = (ol >> 2) & 63;
  }
  int wrow[3], wcol[3];
#pragma unroll
  for (int i = 0; i < 3; ++i) {
    int off = i * 8192 + tid * 16;
    int ol = off ^ (((off >> 7) & 7) << 4);
    wrow[i] = ol >> 7; wcol[i] = (ol >> 1) & 63;
  }

#define STAGE(k0, buf)                                                          \
  {                                                                             \
    char* xsb_ = lds_raw[buf];                                                  \
    char* wtb_ = lds_raw[buf] + 8192;                                           \
    gload_lds16(x + (size_t)(m0 + xr) * NC + (k0) + xc, xsb_ + tid * 16);       \
    _Pragma("unroll")                                                           \
    for (int i = 0; i < 3; ++i)                                                 \
      gload_lds16(Wt + (size_t)wrow[i] * NC + (k0) + wcol[i],                   \
                  wtb_ + i * 8192 + tid * 16);                                  \
  }

  for (int rep = 0; rep < 2; ++rep) {    // DIAGNOSTIC repeat (idempotent)
    f32x4 acc[3];
#pragma unroll
    for (int f = 0; f < 3; ++f) acc[f] = (f32x4){0.f, 0.f, 0.f, 0.f};

    STAGE(0, 0);
    __syncthreads();
    int cur = 0;
    for (int t = 0; t < 16; ++t) {
      if (t + 1 < 16) STAGE((t + 1) * 64, cur ^ 1);
      const char* xsb = lds_raw[cur];
      const char* wtb = lds_raw[cur] + 8192;
      const int r = wr * 16 + l15;
#pragma unroll
      for (int s = 0; s < 2; ++s) {
        int o1 = (r * 256 + s * 128 + hi * 32) ^ ((r & 7) << 4);
        int o2 = (r * 256 + s * 128 + hi * 32 + 16) ^ ((r & 7) << 4);
        float4 q0 = *(const float4*)(xsb + o1);
        float4 q1 = *(const float4*)(xsb + o2);
        bf16x8 a;
        a[0] = f2bf(q0.x); a[1] = f2bf(q0.y); a[2] = f2bf(q0.z); a[3] = f2bf(q0.w);
        a[4] = f2bf(q1.x); a[5] = f2bf(q1.y); a[6] = f2bf(q1.z); a[7] = f2bf(q1.w);
#pragma unroll
        for (int f = 0; f < 3; ++f) {
          int c = wc * 48 + f * 16 + l15;
          int ob = (c * 128 + s * 64 + hi * 16) ^ ((c & 7) << 4);
          bf16x8 b = *(const bf16x8*)(wtb + ob);
          acc[f] = MFMA(a, b, acc[f]);
        }
      }
      __syncthreads();
      cur ^= 1;
    }

    // epilogue: Q,K row-major [t][h]; V transposed [(b*64+h)][t]
#pragma unroll
    for (int f = 0; f < 3; ++f) {
      int c = wc * 48 + f * 16 + l15;
      int mat = c >> 6, h = c & 63;
      if (mat < 2) {
        short* dst = (mat == 0) ? Qo : Ko;
#pragma unroll
        for (int r = 0; r < 4; ++r) {
          int t = m0 + wr * 16 + hi * 4 + r;
          dst[(size_t)t * NH + h] = f2bf(acc[f][r]);
        }
      } else {
        int bb = m0 >> 11;
        int t0 = (m0 & 2047) + wr * 16 + hi * 4;
        short4 v;
        v.x = f2bf(acc[f][0]); v.y = f2bf(acc[f][1]);
        v.z = f2bf(acc[f][2]); v.w = f2bf(acc[f][3]);
        *(short4*)(VTo + ((size_t)(bb * 64 + h)) * NT + t0) = v;
      }
    }
    __syncthreads();                     // LDS safe for next rep
  }
#undef STAGE
}

// ---------------------------------------------------------------------------
// Kernel 2: FUSED attention v3 (R8-proven) with REP=3 diagnostic loop.
// Shift-free softmax: P = exp2(S'), no max reduce; one shfl reduce after
// the k-loop; in-LDS 4-way combine.
// ---------------------------------------------------------------------------
__global__ __launch_bounds__(256, 2) void attn_fused(const short* __restrict__ Q,
                                                     const short* __restrict__ K,
                                                     const short* __restrict__ Vt,
                                                     float* __restrict__ out) {
  __shared__ short PO[4][32][72];        // per-wave P transpose, then partial O
  __shared__ float Ls[4][32];            // per-wave row sums

  const int tid = threadIdx.x;
  const int lane = tid & 63;
  const int wave = tid >> 6;             // 0..3
  const int l15 = lane & 15;
  const int hi = lane >> 4;
  const int kg = hi * 8;

  const int bid = blockIdx.x;
  const int half = bid >> 8;
  const int rr = bid & 255;
  const int b = rr >> 5;
  const int i = rr & 31;
  const int qt = (half == 0) ? (63 - i) : i;   // heavy first -> CU pairing
  const int ktmax = qt >> 1;
  const int q0 = qt * 32;

  bf16x8 qf[2][2];
#pragma unroll
  for (int m = 0; m < 2; ++m)
#pragma unroll
    for (int s = 0; s < 2; ++s)
      qf[m][s] = *(const bf16x8*)(Q + ((size_t)b * NT + q0 + m * 16 + l15) * NH +
                                  s * 32 + kg);

#define LOAD_K(dst, kt_)                                                        \
  {                                                                             \
    const short* kb_ = K + ((size_t)b * NT + (kt_) * 64) * NH;                  \
    _Pragma("unroll") for (int n = 0; n < 4; ++n)                               \
    _Pragma("unroll") for (int s = 0; s < 2; ++s)                               \
      dst[n][s] = *(const bf16x8*)(kb_ + (n * 16 + l15) * NH + s * 32 + kg);    \
  }
#define LOAD_V(dst, kt_)                                                        \
  {                                                                             \
    _Pragma("unroll") for (int f = 0; f < 4; ++f)                               \
    _Pragma("unroll") for (int s = 0; s < 2; ++s)                               \
      dst[f][s] = *(const bf16x8*)(Vt + ((size_t)(b * 64 + f * 16 + l15)) * NT +\
                                   (kt_) * 64 + s * 32 + kg);                   \
  }

  for (int rep = 0; rep < 3; ++rep) {    // DIAGNOSTIC repeat (idempotent)
    __syncthreads();                     // prior rep's combine reads done

    f32x4 oacc[2][4];
#pragma unroll
    for (int m = 0; m < 2; ++m)
#pragma unroll
      for (int f = 0; f < 4; ++f) oacc[m][f] = (f32x4){0.f, 0.f, 0.f, 0.f};
    float ps[2][4];
#pragma unroll
    for (int m = 0; m < 2; ++m)
#pragma unroll
      for (int r = 0; r < 4; ++r) ps[m][r] = 0.f;

    int kt = wave;
    bf16x8 kf[4][2];
    if (kt <= ktmax) LOAD_K(kf, kt);

    for (; kt <= ktmax; kt += 4) {
      bf16x8 vf[4][2];
      LOAD_V(vf, kt);                    // issue now, consumed after exp

      f32x4 S[2][4];
#pragma unroll
      for (int m = 0; m < 2; ++m)
#pragma unroll
        for (int n = 0; n < 4; ++n) {
          S[m][n] = (f32x4){0.f, 0.f, 0.f, 0.f};
          S[m][n] = MFMA(qf[m][0], kf[n][0], S[m][n]);
          S[m][n] = MFMA(qf[m][1], kf[n][1], S[m][n]);
        }

      bf16x8 kn[4][2];
      const bool more = (kt + 4) <= ktmax;
      if (more) LOAD_K(kn, kt + 4);      // prefetch next K under exp/PV

      if (kt == ktmax) {                 // causal mask (diagonal tile)
#pragma unroll
        for (int m = 0; m < 2; ++m)
#pragma unroll
          for (int n = 0; n < 4; ++n)
#pragma unroll
            for (int r = 0; r < 4; ++r)
              if (kt * 64 + n * 16 + l15 > q0 + m * 16 + hi * 4 + r)
                S[m][n][r] = -INFINITY;  // exp2 -> 0
      }
#pragma unroll
      for (int m = 0; m < 2; ++m)
#pragma unroll
        for (int n = 0; n < 4; ++n)
#pragma unroll
          for (int r = 0; r < 4; ++r) {
            float p = __builtin_amdgcn_exp2f(S[m][n][r]);
            S[m][n][r] = p;
            ps[m][r] += p;
          }

      // P transpose through per-wave LDS (wave-internal, no barrier)
#pragma unroll
      for (int m = 0; m < 2; ++m)
#pragma unroll
        for (int n = 0; n < 4; ++n)
#pragma unroll
          for (int r = 0; r < 4; ++r)
            PO[wave][m * 16 + hi * 4 + r][n * 16 + l15] = f2bf(S[m][n][r]);

      bf16x8 pa[2][2];
#pragma unroll
      for (int m = 0; m < 2; ++m)
#pragma unroll
        for (int s = 0; s < 2; ++s)
          pa[m][s] = *(const bf16x8*)&PO[wave][m * 16 + l15][s * 32 + kg];
#pragma unroll
      for (int m = 0; m < 2; ++m)
#pragma unroll
        for (int f = 0; f < 4; ++f) {
          oacc[m][f] = MFMA(pa[m][0], vf[f][0], oacc[m][f]);
          oacc[m][f] = MFMA(pa[m][1], vf[f][1], oacc[m][f]);
        }
      if (more) {
#pragma unroll
        for (int n = 0; n < 4; ++n)
#pragma unroll
          for (int s = 0; s < 2; ++s) kf[n][s] = kn[n][s];
      }
    }

    // ONE row-sum reduce over the 16 key-lanes
#pragma unroll
    for (int d = 1; d < 16; d <<= 1)
#pragma unroll
      for (int m = 0; m < 2; ++m)
#pragma unroll
        for (int r = 0; r < 4; ++r) ps[m][r] += __shfl_xor(ps[m][r], d);

    if (l15 == 0) {
#pragma unroll
      for (int m = 0; m < 2; ++m)
#pragma unroll
        for (int r = 0; r < 4; ++r)
          Ls[wave][m * 16 + hi * 4 + r] = ps[m][r];
    }
#pragma unroll
    for (int m = 0; m < 2; ++m)
#pragma unroll
      for (int f = 0; f < 4; ++f)
#pragma unroll
        for (int r = 0; r < 4; ++r)
          PO[wave][m * 16 + hi * 4 + r][f * 16 + l15] = f2bf(oacc[m][f][r]);
    __syncthreads();

    // combine: plain sums (all waves share shift 0). thread -> row, 8 cols.
    {
      const int row = tid >> 3;
      const int c0 = (tid & 7) * 8;
      float L = 0.f;
      float o[8] = {0.f, 0.f, 0.f, 0.f, 0.f, 0.f, 0.f, 0.f};
#pragma unroll
      for (int w = 0; w < 4; ++w) {
        L += Ls[w][row];
        short4 v0 = *(const short4*)&PO[w][row][c0];
        short4 v1 = *(const short4*)&PO[w][row][c0 + 4];
        o[0] += bf2f(v0.x); o[1] += bf2f(v0.y); o[2] += bf2f(v0.z); o[3] += bf2f(v0.w);
        o[4] += bf2f(v1.x); o[5] += bf2f(v1.y); o[6] += bf2f(v1.z); o[7] += bf2f(v1.w);
      }
      float inv = 1.f / L;
      float* po = out + ((size_t)b * NT + q0 + row) * NH + c0;
      float4 r0 = {o[0] * inv, o[1] * inv, o[2] * inv, o[3] * inv};
      float4 r1 = {o[4] * inv, o[5] * inv, o[6] * inv, o[7] * inv};
      *(float4*)po = r0;
      *(float4*)(po + 4) = r1;
    }
  }
#undef LOAD_K
#undef LOAD_V
}

// ---------------------------------------------------------------------------
extern "C" void kernel_launch(void* const* d_in, const int* in_sizes, int n_in,
                              void* d_out, int out_size, void* d_ws, size_t ws_size,
                              hipStream_t stream) {
  const float* x  = (const float*)d_in[0];
  const float* Wq = (const float*)d_in[1];
  const float* Wk = (const float*)d_in[2];
  const float* Wv = (const float*)d_in[3];
  float* out = (float*)d_out;

  char* ws = (char*)d_ws;
  short* Wt = (short*)ws;                          // 384 KB
  short* Qb = (short*)(ws + (size_t)(1 << 20));    // 2 MB
  short* Kb = (short*)(ws + (size_t)(3 << 20));    // 2 MB
  short* Vt = (short*)(ws + (size_t)(5 << 20));    // 2 MB (transposed V)

  hipLaunchKernelGGL(w_prep, dim3(48), dim3(256), 0, stream, Wq, Wk, Wv, Wt);
  hipLaunchKernelGGL(qkv_proj, dim3(512), dim3(512), 0, stream, x, Wt, Qb, Kb, Vt);
  hipLaunchKernelGGL(attn_fused, dim3(512), dim3(256), 0, stream, Qb, Kb, Vt, out);
}

// Round 14
// 61.020 us; speedup vs baseline: 1.5745x; 1.5745x over previous
//
#include <hip/hip_runtime.h>
#include <hip/hip_bf16.h>
#include <stdint.h>

#define NB 8
#define NT 2048
#define NC 1024
#define NH 64

typedef __attribute__((ext_vector_type(8))) short bf16x8;
typedef __attribute__((ext_vector_type(4))) float f32x4;

#define MFMA(a, b, c) __builtin_amdgcn_mfma_f32_16x16x32_bf16((a), (b), (c), 0, 0, 0)

static __device__ __forceinline__ short f2bf(float f) {
  union { float f; uint32_t u; } v; v.f = f;
  uint32_t r = v.u + 0x7FFFu + ((v.u >> 16) & 1u);  // RNE bf16
  return (short)(r >> 16);
}
static __device__ __forceinline__ float bf2f(short h) {
  union { uint32_t u; float f; } v; v.u = ((uint32_t)(uint16_t)h) << 16;
  return v.f;
}
static __device__ __forceinline__ void gload_lds16(const void* g, void* l) {
  __builtin_amdgcn_global_load_lds(
      (const __attribute__((address_space(1))) uint32_t*)g,
      (__attribute__((address_space(3))) uint32_t*)l, 16, 0, 0);
}

// ---------------------------------------------------------------------------
// Kernel 0: build Wt[192][1024] bf16 = concat(Wq^T * 0.125*log2e, Wk^T, Wv^T)
// ---------------------------------------------------------------------------
__global__ __launch_bounds__(256) void w_prep(const float* __restrict__ Wq,
                                              const float* __restrict__ Wk,
                                              const float* __restrict__ Wv,
                                              short* __restrict__ Wt) {
  __shared__ short tile[64][68];
  const int blk = blockIdx.x;          // 48 blocks: 3 mats x 16 k-tiles
  const int mat = blk / 16;
  const int k0 = (blk % 16) * 64;
  const float* W = (mat == 0) ? Wq : (mat == 1) ? Wk : Wv;
  const float scale = (mat == 0) ? 0.125f * 1.44269504088896f : 1.0f;
  const int tid = threadIdx.x;
  {
    int kk = tid >> 2;
    int h0 = (tid & 3) * 16;
    const float* src = W + (size_t)(k0 + kk) * NH + h0;
#pragma unroll
    for (int i = 0; i < 16; ++i) tile[kk][h0 + i] = f2bf(src[i] * scale);
  }
  __syncthreads();
  {
    int j = tid >> 2;
    int kk0 = (tid & 3) * 16;
    bf16x8 t0, t1;
#pragma unroll
    for (int i = 0; i < 8; ++i) { t0[i] = tile[kk0 + i][j]; t1[i] = tile[kk0 + 8 + i][j]; }
    short* dst = Wt + (size_t)(mat * 64 + j) * NC + k0 + kk0;
    *(bf16x8*)dst = t0;
    *(bf16x8*)(dst + 8) = t1;
  }
}

// ---------------------------------------------------------------------------
// Kernel 1: QKV projection v5 (R8-proven, unchanged). 512 blocks x 32 rows,
// 8 waves (512 thr). K-step 64, double-buffered global_load_lds w16,
// XOR-swizzled source. V transposed: VTo[(b*64+h)][t].
// ---------------------------------------------------------------------------
__global__ __launch_bounds__(512) void qkv_proj(const float* __restrict__ x,
                                                const short* __restrict__ Wt,
                                                short* __restrict__ Qo,
                                                short* __restrict__ Ko,
                                                short* __restrict__ VTo) {
  __shared__ char lds_raw[2][32768];
  const int tid = threadIdx.x;
  const int lane = tid & 63;
  const int wave = tid >> 6;             // 0..7
  const int l15 = lane & 15;
  const int hi = lane >> 4;
  const int m0 = blockIdx.x * 32;
  const int wr = wave & 1;               // row group (16 rows)
  const int wc = wave >> 1;              // col group (48 cols)

  f32x4 acc[3];
#pragma unroll
  for (int f = 0; f < 3; ++f) acc[f] = (f32x4){0.f, 0.f, 0.f, 0.f};

  int xr, xc;
  {
    int off = tid * 16;
    int ol = off ^ (((off >> 8) & 7) << 4);
    xr = ol >> 8; xc = (ol >> 2) & 63;
  }
  int wrow[3], wcol[3];
#pragma unroll
  for (int i = 0; i < 3; ++i) {
    int off = i * 8192 + tid * 16;
    int ol = off ^ (((off >> 7) & 7) << 4);
    wrow[i] = ol >> 7; wcol[i] = (ol >> 1) & 63;
  }

#define STAGE(k0, buf)                                                          \
  {                                                                             \
    char* xsb_ = lds_raw[buf];                                                  \
    char* wtb_ = lds_raw[buf] + 8192;                                           \
    gload_lds16(x + (size_t)(m0 + xr) * NC + (k0) + xc, xsb_ + tid * 16);       \
    _Pragma("unroll")                                                           \
    for (int i = 0; i < 3; ++i)                                                 \
      gload_lds16(Wt + (size_t)wrow[i] * NC + (k0) + wcol[i],                   \
                  wtb_ + i * 8192 + tid * 16);                                  \
  }

  STAGE(0, 0);
  __syncthreads();
  int cur = 0;
  for (int t = 0; t < 16; ++t) {
    if (t + 1 < 16) STAGE((t + 1) * 64, cur ^ 1);
    const char* xsb = lds_raw[cur];
    const char* wtb = lds_raw[cur] + 8192;
    const int r = wr * 16 + l15;
#pragma unroll
    for (int s = 0; s < 2; ++s) {
      int o1 = (r * 256 + s * 128 + hi * 32) ^ ((r & 7) << 4);
      int o2 = (r * 256 + s * 128 + hi * 32 + 16) ^ ((r & 7) << 4);
      float4 q0 = *(const float4*)(xsb + o1);
      float4 q1 = *(const float4*)(xsb + o2);
      bf16x8 a;
      a[0] = f2bf(q0.x); a[1] = f2bf(q0.y); a[2] = f2bf(q0.z); a[3] = f2bf(q0.w);
      a[4] = f2bf(q1.x); a[5] = f2bf(q1.y); a[6] = f2bf(q1.z); a[7] = f2bf(q1.w);
#pragma unroll
      for (int f = 0; f < 3; ++f) {
        int c = wc * 48 + f * 16 + l15;
        int ob = (c * 128 + s * 64 + hi * 16) ^ ((c & 7) << 4);
        bf16x8 b = *(const bf16x8*)(wtb + ob);
        acc[f] = MFMA(a, b, acc[f]);
      }
    }
    __syncthreads();
    cur ^= 1;
  }
#undef STAGE

#pragma unroll
  for (int f = 0; f < 3; ++f) {
    int c = wc * 48 + f * 16 + l15;
    int mat = c >> 6, h = c & 63;
    if (mat < 2) {
      short* dst = (mat == 0) ? Qo : Ko;
#pragma unroll
      for (int r = 0; r < 4; ++r) {
        int t = m0 + wr * 16 + hi * 4 + r;
        dst[(size_t)t * NH + h] = f2bf(acc[f][r]);
      }
    } else {
      int bb = m0 >> 11;
      int t0 = (m0 & 2047) + wr * 16 + hi * 4;
      short4 v;
      v.x = f2bf(acc[f][0]); v.y = f2bf(acc[f][1]);
      v.z = f2bf(acc[f][2]); v.w = f2bf(acc[f][3]);
      *(short4*)(VTo + ((size_t)(bb * 64 + h)) * NT + t0) = v;
    }
  }
}

// ---------------------------------------------------------------------------
// Kernel 2: FUSED attention v5 — 16-ROW q-tiles for 2x TLP (grid was the
// occupancy limiter: R13 counters showed 2 blocks/CU, all pipes <20%).
// Grid 1024 blocks (b, qt of 16 q-rows), 4 waves; wave w takes k-tiles
// {w, w+4, ...} (64 keys each). Shift-free softmax (P=exp2(S'), scale folded
// in Wq); one shfl reduce after k-loop; in-LDS 4-way plain-sum combine.
// launch_bounds(256,4): VGPR cap 128, demand ~110 (no kn prefetch, m-dim
// removed) -> 4 blocks/CU.
// ---------------------------------------------------------------------------
__global__ __launch_bounds__(256, 4) void attn_fused(const short* __restrict__ Q,
                                                     const short* __restrict__ K,
                                                     const short* __restrict__ Vt,
                                                     float* __restrict__ out) {
  __shared__ short PO[4][16][72];        // per-wave P transpose, then partial O
  __shared__ float Ls[4][16];            // per-wave row sums

  const int tid = threadIdx.x;
  const int lane = tid & 63;
  const int wave = tid >> 6;             // 0..3
  const int l15 = lane & 15;
  const int hi = lane >> 4;
  const int kg = hi * 8;

  const int bid = blockIdx.x;
  const int half = bid >> 9;             // 0: heavy qt, 1: light qt
  const int rr = bid & 511;
  const int b = rr >> 6;
  const int i = rr & 63;
  const int qt = (half == 0) ? (127 - i) : i;  // heavy first -> CU mixing
  const int ktmax = qt >> 2;             // last 64-key tile touching row qt*16+15
  const int q0 = qt * 16;

  bf16x8 qf[2];
#pragma unroll
  for (int s = 0; s < 2; ++s)
    qf[s] = *(const bf16x8*)(Q + ((size_t)b * NT + q0 + l15) * NH + s * 32 + kg);

  f32x4 oacc[4];
#pragma unroll
  for (int f = 0; f < 4; ++f) oacc[f] = (f32x4){0.f, 0.f, 0.f, 0.f};
  float ps[4];                           // per-lane row-sum partials
#pragma unroll
  for (int r = 0; r < 4; ++r) ps[r] = 0.f;

  for (int kt = wave; kt <= ktmax; kt += 4) {
    // K fragments (B-op of QK^T) and V^T fragments (B-op of PV)
    const short* kb = K + ((size_t)b * NT + kt * 64) * NH;
    bf16x8 kf[4][2], vf[4][2];
#pragma unroll
    for (int n = 0; n < 4; ++n)
#pragma unroll
      for (int s = 0; s < 2; ++s)
        kf[n][s] = *(const bf16x8*)(kb + (n * 16 + l15) * NH + s * 32 + kg);
#pragma unroll
    for (int f = 0; f < 4; ++f)
#pragma unroll
      for (int s = 0; s < 2; ++s)
        vf[f][s] = *(const bf16x8*)(Vt + ((size_t)(b * 64 + f * 16 + l15)) * NT +
                                    kt * 64 + s * 32 + kg);

    f32x4 S[4];
#pragma unroll
    for (int n = 0; n < 4; ++n) {
      S[n] = (f32x4){0.f, 0.f, 0.f, 0.f};
      S[n] = MFMA(qf[0], kf[n][0], S[n]);
      S[n] = MFMA(qf[1], kf[n][1], S[n]);
    }
    if (kt == ktmax) {                   // causal mask (diagonal tile)
#pragma unroll
      for (int n = 0; n < 4; ++n)
#pragma unroll
        for (int r = 0; r < 4; ++r)
          if (kt * 64 + n * 16 + l15 > q0 + hi * 4 + r)
            S[n][r] = -INFINITY;         // exp2 -> 0
    }
    // P = exp2(S); accumulate per-lane row partial sums
#pragma unroll
    for (int n = 0; n < 4; ++n)
#pragma unroll
      for (int r = 0; r < 4; ++r) {
        float p = __builtin_amdgcn_exp2f(S[n][r]);
        S[n][r] = p;
        ps[r] += p;
      }

    // P transpose through per-wave LDS (wave-internal, no barrier)
#pragma unroll
    for (int n = 0; n < 4; ++n)
#pragma unroll
      for (int r = 0; r < 4; ++r)
        PO[wave][hi * 4 + r][n * 16 + l15] = f2bf(S[n][r]);

    bf16x8 pa[2];
#pragma unroll
    for (int s = 0; s < 2; ++s)
      pa[s] = *(const bf16x8*)&PO[wave][l15][s * 32 + kg];
#pragma unroll
    for (int f = 0; f < 4; ++f) {
      oacc[f] = MFMA(pa[0], vf[f][0], oacc[f]);
      oacc[f] = MFMA(pa[1], vf[f][1], oacc[f]);
    }
  }

  // ONE row-sum reduce over the 16 key-lanes (idle waves publish zeros)
#pragma unroll
  for (int d = 1; d < 16; d <<= 1)
#pragma unroll
    for (int r = 0; r < 4; ++r) ps[r] += __shfl_xor(ps[r], d);

  if (l15 == 0) {
#pragma unroll
    for (int r = 0; r < 4; ++r) Ls[wave][hi * 4 + r] = ps[r];
  }
#pragma unroll
  for (int f = 0; f < 4; ++f)
#pragma unroll
    for (int r = 0; r < 4; ++r)
      PO[wave][hi * 4 + r][f * 16 + l15] = f2bf(oacc[f][r]);
  __syncthreads();

  // combine: plain sums (all waves share shift 0). thread -> row, 4 cols.
  {
    const int row = tid >> 4;            // 0..15
    const int c0 = (tid & 15) * 4;
    float L = 0.f;
    float o[4] = {0.f, 0.f, 0.f, 0.f};
#pragma unroll
    for (int w = 0; w < 4; ++w) {
      L += Ls[w][row];
      short4 v = *(const short4*)&PO[w][row][c0];
      o[0] += bf2f(v.x); o[1] += bf2f(v.y);
      o[2] += bf2f(v.z); o[3] += bf2f(v.w);
    }
    float inv = 1.f / L;
    float4 res = {o[0] * inv, o[1] * inv, o[2] * inv, o[3] * inv};
    *(float4*)(out + ((size_t)b * NT + q0 + row) * NH + c0) = res;
  }
}

// ---------------------------------------------------------------------------
extern "C" void kernel_launch(void* const* d_in, const int* in_sizes, int n_in,
                              void* d_out, int out_size, void* d_ws, size_t ws_size,
                              hipStream_t stream) {
  const float* x  = (const float*)d_in[0];
  const float* Wq = (const float*)d_in[1];
  const float* Wk = (const float*)d_in[2];
  const float* Wv = (const float*)d_in[3];
  float* out = (float*)d_out;

  char* ws = (char*)d_ws;
  short* Wt = (short*)ws;                          // 384 KB
  short* Qb = (short*)(ws + (size_t)(1 << 20));    // 2 MB
  short* Kb = (short*)(ws + (size_t)(3 << 20));    // 2 MB
  short* Vt = (short*)(ws + (size_t)(5 << 20));    // 2 MB (transposed V)

  hipLaunchKernelGGL(w_prep, dim3(48), dim3(256), 0, stream, Wq, Wk, Wv, Wt);
  hipLaunchKernelGGL(qkv_proj, dim3(512), dim3(512), 0, stream, x, Wt, Qb, Kb, Vt);
  hipLaunchKernelGGL(attn_fused, dim3(1024), dim3(256), 0, stream, Qb, Kb, Vt, out);
}

// Round 15
// 45.222 us; speedup vs baseline: 2.1245x; 1.3494x over previous
//
#include <hip/hip_runtime.h>
#include <hip/hip_bf16.h>
#include <stdint.h>

#define NB 8
#define NT 2048
#define NC 1024
#define NH 64

typedef __attribute__((ext_vector_type(8))) short bf16x8;
typedef __attribute__((ext_vector_type(4))) float f32x4;

#define MFMA(a, b, c) __builtin_amdgcn_mfma_f32_16x16x32_bf16((a), (b), (c), 0, 0, 0)

static __device__ __forceinline__ short f2bf(float f) {
  union { float f; uint32_t u; } v; v.f = f;
  uint32_t r = v.u + 0x7FFFu + ((v.u >> 16) & 1u);  // RNE bf16
  return (short)(r >> 16);
}
static __device__ __forceinline__ float bf2f(short h) {
  union { uint32_t u; float f; } v; v.u = ((uint32_t)(uint16_t)h) << 16;
  return v.f;
}
static __device__ __forceinline__ void gload_lds16(const void* g, void* l) {
  __builtin_amdgcn_global_load_lds(
      (const __attribute__((address_space(1))) uint32_t*)g,
      (__attribute__((address_space(3))) uint32_t*)l, 16, 0, 0);
}

// ---------------------------------------------------------------------------
// Kernel 0: build Wt[192][1024] bf16 = concat(Wq^T * 0.125*log2e, Wk^T, Wv^T)
// ---------------------------------------------------------------------------
__global__ __launch_bounds__(256) void w_prep(const float* __restrict__ Wq,
                                              const float* __restrict__ Wk,
                                              const float* __restrict__ Wv,
                                              short* __restrict__ Wt) {
  __shared__ short tile[64][68];
  const int blk = blockIdx.x;          // 48 blocks: 3 mats x 16 k-tiles
  const int mat = blk / 16;
  const int k0 = (blk % 16) * 64;
  const float* W = (mat == 0) ? Wq : (mat == 1) ? Wk : Wv;
  const float scale = (mat == 0) ? 0.125f * 1.44269504088896f : 1.0f;
  const int tid = threadIdx.x;
  {
    int kk = tid >> 2;
    int h0 = (tid & 3) * 16;
    const float* src = W + (size_t)(k0 + kk) * NH + h0;
#pragma unroll
    for (int i = 0; i < 16; ++i) tile[kk][h0 + i] = f2bf(src[i] * scale);
  }
  __syncthreads();
  {
    int j = tid >> 2;
    int kk0 = (tid & 3) * 16;
    bf16x8 t0, t1;
#pragma unroll
    for (int i = 0; i < 8; ++i) { t0[i] = tile[kk0 + i][j]; t1[i] = tile[kk0 + 8 + i][j]; }
    short* dst = Wt + (size_t)(mat * 64 + j) * NC + k0 + kk0;
    *(bf16x8*)dst = t0;
    *(bf16x8*)(dst + 8) = t1;
  }
}

// ---------------------------------------------------------------------------
// Kernel 1: QKV projection v5 (R8-proven, unchanged). 512 blocks x 32 rows,
// 8 waves (512 thr). K-step 64, double-buffered global_load_lds w16,
// XOR-swizzled source. V transposed: VTo[(b*64+h)][t].
// ---------------------------------------------------------------------------
__global__ __launch_bounds__(512) void qkv_proj(const float* __restrict__ x,
                                                const short* __restrict__ Wt,
                                                short* __restrict__ Qo,
                                                short* __restrict__ Ko,
                                                short* __restrict__ VTo) {
  __shared__ char lds_raw[2][32768];
  const int tid = threadIdx.x;
  const int lane = tid & 63;
  const int wave = tid >> 6;             // 0..7
  const int l15 = lane & 15;
  const int hi = lane >> 4;
  const int m0 = blockIdx.x * 32;
  const int wr = wave & 1;               // row group (16 rows)
  const int wc = wave >> 1;              // col group (48 cols)

  f32x4 acc[3];
#pragma unroll
  for (int f = 0; f < 3; ++f) acc[f] = (f32x4){0.f, 0.f, 0.f, 0.f};

  int xr, xc;
  {
    int off = tid * 16;
    int ol = off ^ (((off >> 8) & 7) << 4);
    xr = ol >> 8; xc = (ol >> 2) & 63;
  }
  int wrow[3], wcol[3];
#pragma unroll
  for (int i = 0; i < 3; ++i) {
    int off = i * 8192 + tid * 16;
    int ol = off ^ (((off >> 7) & 7) << 4);
    wrow[i] = ol >> 7; wcol[i] = (ol >> 1) & 63;
  }

#define STAGE(k0, buf)                                                          \
  {                                                                             \
    char* xsb_ = lds_raw[buf];                                                  \
    char* wtb_ = lds_raw[buf] + 8192;                                           \
    gload_lds16(x + (size_t)(m0 + xr) * NC + (k0) + xc, xsb_ + tid * 16);       \
    _Pragma("unroll")                                                           \
    for (int i = 0; i < 3; ++i)                                                 \
      gload_lds16(Wt + (size_t)wrow[i] * NC + (k0) + wcol[i],                   \
                  wtb_ + i * 8192 + tid * 16);                                  \
  }

  STAGE(0, 0);
  __syncthreads();
  int cur = 0;
  for (int t = 0; t < 16; ++t) {
    if (t + 1 < 16) STAGE((t + 1) * 64, cur ^ 1);
    const char* xsb = lds_raw[cur];
    const char* wtb = lds_raw[cur] + 8192;
    const int r = wr * 16 + l15;
#pragma unroll
    for (int s = 0; s < 2; ++s) {
      int o1 = (r * 256 + s * 128 + hi * 32) ^ ((r & 7) << 4);
      int o2 = (r * 256 + s * 128 + hi * 32 + 16) ^ ((r & 7) << 4);
      float4 q0 = *(const float4*)(xsb + o1);
      float4 q1 = *(const float4*)(xsb + o2);
      bf16x8 a;
      a[0] = f2bf(q0.x); a[1] = f2bf(q0.y); a[2] = f2bf(q0.z); a[3] = f2bf(q0.w);
      a[4] = f2bf(q1.x); a[5] = f2bf(q1.y); a[6] = f2bf(q1.z); a[7] = f2bf(q1.w);
#pragma unroll
      for (int f = 0; f < 3; ++f) {
        int c = wc * 48 + f * 16 + l15;
        int ob = (c * 128 + s * 64 + hi * 16) ^ ((c & 7) << 4);
        bf16x8 b = *(const bf16x8*)(wtb + ob);
        acc[f] = MFMA(a, b, acc[f]);
      }
    }
    __syncthreads();
    cur ^= 1;
  }
#undef STAGE

#pragma unroll
  for (int f = 0; f < 3; ++f) {
    int c = wc * 48 + f * 16 + l15;
    int mat = c >> 6, h = c & 63;
    if (mat < 2) {
      short* dst = (mat == 0) ? Qo : Ko;
#pragma unroll
      for (int r = 0; r < 4; ++r) {
        int t = m0 + wr * 16 + hi * 4 + r;
        dst[(size_t)t * NH + h] = f2bf(acc[f][r]);
      }
    } else {
      int bb = m0 >> 11;
      int t0 = (m0 & 2047) + wr * 16 + hi * 4;
      short4 v;
      v.x = f2bf(acc[f][0]); v.y = f2bf(acc[f][1]);
      v.z = f2bf(acc[f][2]); v.w = f2bf(acc[f][3]);
      *(short4*)(VTo + ((size_t)(bb * 64 + h)) * NT + t0) = v;
    }
  }
}

// ---------------------------------------------------------------------------
// Kernel 2: FUSED attention v6 — v3 + V via wave-private LDS DMA.
// V's 8 reg-loads (which serialized under VGPR recycling) become 8
// global_load_lds (zero VGPR) into Vs[wave] (8KB, single-buffer; safe:
// PV ds_reads retire before next iter's DMA issues, all wave-internal).
// XOR swizzle both-sides: stage source chunk j^(h&7); read byte ^(h&7)<<4
// -> conflict-free ds_read_b128. Explicit vmcnt(0)+sched_barrier gates the
// Vs reads. Rest identical to v3 (shift-free softmax, 4-way LDS combine).
// ---------------------------------------------------------------------------
__global__ __launch_bounds__(256, 2) void attn_fused(const short* __restrict__ Q,
                                                     const short* __restrict__ K,
                                                     const short* __restrict__ Vt,
                                                     float* __restrict__ out) {
  __shared__ short PO[4][32][72];        // per-wave P transpose, then partial O
  __shared__ float Ls[4][32];            // per-wave row sums
  __shared__ short Vs[4][4096];          // per-wave V^T tile (swizzled), 8KB

  const int tid = threadIdx.x;
  const int lane = tid & 63;
  const int wave = tid >> 6;             // 0..3
  const int l15 = lane & 15;
  const int hi = lane >> 4;
  const int kg = hi * 8;

  const int bid = blockIdx.x;
  const int half = bid >> 8;
  const int rr = bid & 255;
  const int b = rr >> 5;
  const int i = rr & 31;
  const int qt = (half == 0) ? (63 - i) : i;   // heavy first -> CU pairing
  const int ktmax = qt >> 1;
  const int q0 = qt * 32;

  bf16x8 qf[2][2];
#pragma unroll
  for (int m = 0; m < 2; ++m)
#pragma unroll
    for (int s = 0; s < 2; ++s)
      qf[m][s] = *(const bf16x8*)(Q + ((size_t)b * NT + q0 + m * 16 + l15) * NH +
                                  s * 32 + kg);

  f32x4 oacc[2][4];
#pragma unroll
  for (int m = 0; m < 2; ++m)
#pragma unroll
    for (int f = 0; f < 4; ++f) oacc[m][f] = (f32x4){0.f, 0.f, 0.f, 0.f};
  float ps[2][4];                        // per-lane row-sum partials
#pragma unroll
  for (int m = 0; m < 2; ++m)
#pragma unroll
    for (int r = 0; r < 4; ++r) ps[m][r] = 0.f;

#define LOAD_K(dst, kt_)                                                        \
  {                                                                             \
    const short* kb_ = K + ((size_t)b * NT + (kt_) * 64) * NH;                  \
    _Pragma("unroll") for (int n = 0; n < 4; ++n)                               \
    _Pragma("unroll") for (int s = 0; s < 2; ++s)                               \
      dst[n][s] = *(const bf16x8*)(kb_ + (n * 16 + l15) * NH + s * 32 + kg);    \
  }
// V^T tile stage: lane ln covers h = i*8 + ln/8, 16B chunk (ln&7), with
// source chunk pre-swizzled by ^(h&7) so swizzled read sees linear data.
#define STAGE_V(kt_)                                                            \
  {                                                                             \
    _Pragma("unroll") for (int iv = 0; iv < 8; ++iv) {                          \
      int h_ = iv * 8 + (lane >> 3);                                            \
      int sb_ = (((lane & 7) * 16) ^ ((h_ & 7) << 4)) >> 1;                     \
      gload_lds16(Vt + ((size_t)(b * 64 + h_)) * NT + (kt_) * 64 + sb_,         \
                  &Vs[wave][iv * 512]);                                         \
    }                                                                           \
  }

  int kt = wave;
  bf16x8 kf[4][2];
  if (kt <= ktmax) LOAD_K(kf, kt);

  for (; kt <= ktmax; kt += 4) {
    STAGE_V(kt);                         // DMA; completes under QK+softmax

    f32x4 S[2][4];
#pragma unroll
    for (int m = 0; m < 2; ++m)
#pragma unroll
      for (int n = 0; n < 4; ++n) {
        S[m][n] = (f32x4){0.f, 0.f, 0.f, 0.f};
        S[m][n] = MFMA(qf[m][0], kf[n][0], S[m][n]);
        S[m][n] = MFMA(qf[m][1], kf[n][1], S[m][n]);
      }

    bf16x8 kn[4][2];
    const bool more = (kt + 4) <= ktmax;
    if (more) LOAD_K(kn, kt + 4);        // prefetch next K

    if (kt == ktmax) {                   // causal mask (diagonal tile)
#pragma unroll
      for (int m = 0; m < 2; ++m)
#pragma unroll
        for (int n = 0; n < 4; ++n)
#pragma unroll
          for (int r = 0; r < 4; ++r)
            if (kt * 64 + n * 16 + l15 > q0 + m * 16 + hi * 4 + r)
              S[m][n][r] = -INFINITY;    // exp2 -> 0
    }
    // P = exp2(S); accumulate per-lane row partial sums
#pragma unroll
    for (int m = 0; m < 2; ++m)
#pragma unroll
      for (int n = 0; n < 4; ++n)
#pragma unroll
        for (int r = 0; r < 4; ++r) {
          float p = __builtin_amdgcn_exp2f(S[m][n][r]);
          S[m][n][r] = p;
          ps[m][r] += p;
        }

    // P transpose through per-wave LDS (wave-internal, no barrier)
#pragma unroll
    for (int m = 0; m < 2; ++m)
#pragma unroll
      for (int n = 0; n < 4; ++n)
#pragma unroll
        for (int r = 0; r < 4; ++r)
          PO[wave][m * 16 + hi * 4 + r][n * 16 + l15] = f2bf(S[m][n][r]);

    bf16x8 pa[2][2];
#pragma unroll
    for (int m = 0; m < 2; ++m)
#pragma unroll
      for (int s = 0; s < 2; ++s)
        pa[m][s] = *(const bf16x8*)&PO[wave][m * 16 + l15][s * 32 + kg];

    // gate: V DMA landed (wave-private; no barrier needed)
    asm volatile("s_waitcnt vmcnt(0)" ::: "memory");
    __builtin_amdgcn_sched_barrier(0);

    bf16x8 vf[4][2];
#pragma unroll
    for (int f = 0; f < 4; ++f)
#pragma unroll
      for (int s = 0; s < 2; ++s) {
        int h_ = f * 16 + l15;
        int ob = h_ * 128 + (((s * 32 + kg) * 2) ^ ((h_ & 7) << 4));
        vf[f][s] = *(const bf16x8*)((const char*)&Vs[wave][0] + ob);
      }
#pragma unroll
    for (int m = 0; m < 2; ++m)
#pragma unroll
      for (int f = 0; f < 4; ++f) {
        oacc[m][f] = MFMA(pa[m][0], vf[f][0], oacc[m][f]);
        oacc[m][f] = MFMA(pa[m][1], vf[f][1], oacc[m][f]);
      }
    if (more) {
#pragma unroll
      for (int n = 0; n < 4; ++n)
#pragma unroll
        for (int s = 0; s < 2; ++s) kf[n][s] = kn[n][s];
    }
  }
#undef LOAD_K
#undef STAGE_V

  // ONE row-sum reduce over the 16 key-lanes
#pragma unroll
  for (int d = 1; d < 16; d <<= 1)
#pragma unroll
    for (int m = 0; m < 2; ++m)
#pragma unroll
      for (int r = 0; r < 4; ++r) ps[m][r] += __shfl_xor(ps[m][r], d);

  if (l15 == 0) {
#pragma unroll
    for (int m = 0; m < 2; ++m)
#pragma unroll
      for (int r = 0; r < 4; ++r)
        Ls[wave][m * 16 + hi * 4 + r] = ps[m][r];
  }
#pragma unroll
  for (int m = 0; m < 2; ++m)
#pragma unroll
    for (int f = 0; f < 4; ++f)
#pragma unroll
      for (int r = 0; r < 4; ++r)
        PO[wave][m * 16 + hi * 4 + r][f * 16 + l15] = f2bf(oacc[m][f][r]);
  __syncthreads();

  // combine: plain sums (all waves share shift 0). thread -> row, 8 cols.
  {
    const int row = tid >> 3;
    const int c0 = (tid & 7) * 8;
    float L = 0.f;
    float o[8] = {0.f, 0.f, 0.f, 0.f, 0.f, 0.f, 0.f, 0.f};
#pragma unroll
    for (int w = 0; w < 4; ++w) {
      L += Ls[w][row];
      short4 v0 = *(const short4*)&PO[w][row][c0];
      short4 v1 = *(const short4*)&PO[w][row][c0 + 4];
      o[0] += bf2f(v0.x); o[1] += bf2f(v0.y); o[2] += bf2f(v0.z); o[3] += bf2f(v0.w);
      o[4] += bf2f(v1.x); o[5] += bf2f(v1.y); o[6] += bf2f(v1.z); o[7] += bf2f(v1.w);
    }
    float inv = 1.f / L;
    float* po = out + ((size_t)b * NT + q0 + row) * NH + c0;
    float4 r0 = {o[0] * inv, o[1] * inv, o[2] * inv, o[3] * inv};
    float4 r1 = {o[4] * inv, o[5] * inv, o[6] * inv, o[7] * inv};
    *(float4*)po = r0;
    *(float4*)(po + 4) = r1;
  }
}

// ---------------------------------------------------------------------------
extern "C" void kernel_launch(void* const* d_in, const int* in_sizes, int n_in,
                              void* d_out, int out_size, void* d_ws, size_t ws_size,
                              hipStream_t stream) {
  const float* x  = (const float*)d_in[0];
  const float* Wq = (const float*)d_in[1];
  const float* Wk = (const float*)d_in[2];
  const float* Wv = (const float*)d_in[3];
  float* out = (float*)d_out;

  char* ws = (char*)d_ws;
  short* Wt = (short*)ws;                          // 384 KB
  short* Qb = (short*)(ws + (size_t)(1 << 20));    // 2 MB
  short* Kb = (short*)(ws + (size_t)(3 << 20));    // 2 MB
  short* Vt = (short*)(ws + (size_t)(5 << 20));    // 2 MB (transposed V)

  hipLaunchKernelGGL(w_prep, dim3(48), dim3(256), 0, stream, Wq, Wk, Wv, Wt);
  hipLaunchKernelGGL(qkv_proj, dim3(512), dim3(512), 0, stream, x, Wt, Qb, Kb, Vt);
  hipLaunchKernelGGL(attn_fused, dim3(512), dim3(256), 0, stream, Qb, Kb, Vt, out);
}